// Round 7
// baseline (280.758 us; speedup 1.0000x reference)
//
#include <hip/hip_runtime.h>
#include <hip/hip_bf16.h>
#include <hip/hip_fp16.h>

#define NT 4096
#define NE 131072
#define NBLK 256

// ws layout (bytes)
#define OFF_DEG  0            // float[4096]
#define OFF_A    16384        // bf16[4096*4096] = 32 MiB
#define OFF_G1T  33570816     // bf16[16][4096]
#define OFF_G2T  33701888     // bf16[32][4096]
#define OFF_G3T  33964032     // bf16[32][4096]
#define OFF_H3   34226176     // bf16[4096][32]
#define OFF_W2T  34488320     // uint[1568]
#define OFF_BAR  34496512     // uint[16] barrier counters
// total ~34.5 MB

typedef __attribute__((ext_vector_type(8))) short bf16x8;
typedef __attribute__((ext_vector_type(4))) float f32x4;

__device__ inline unsigned int align16(unsigned int hi, unsigned int lo) {
#if __has_builtin(__builtin_amdgcn_alignbit)
    return __builtin_amdgcn_alignbit(hi, lo, 16);
#else
    return (lo >> 16) | (hi << 16);
#endif
}

__device__ inline unsigned short bfb(float x) {
    return __hip_bfloat16_raw(__float2bfloat16(x)).x;
}

__device__ inline void atomic_add_bf16(unsigned short* base, unsigned int idx, float v) {
    unsigned long long addr = (unsigned long long)(base + (idx & ~1u));
    unsigned int bits = ((unsigned int)bfb(v)) << ((idx & 1u) * 16);
    asm volatile("global_atomic_pk_add_bf16 %0, %1, off" :: "v"(addr), "v"(bits) : "memory");
}

// grid barrier: all 256 blocks co-resident (1 block/CU). Release fence (wbl2)
// before arrival, acquire fence (inv) after release condition.
__device__ inline void gbar(unsigned int* ctr) {
    __syncthreads();                 // drains block's vmem (compiler emits vmcnt(0))
    if (threadIdx.x == 0) {
        __threadfence();             // agent release: writeback L2
        __hip_atomic_fetch_add(ctr, 1u, __ATOMIC_RELAXED, __HIP_MEMORY_SCOPE_AGENT);
        while (__hip_atomic_load(ctr, __ATOMIC_RELAXED, __HIP_MEMORY_SCOPE_AGENT) < NBLK)
            __builtin_amdgcn_s_sleep(2);
        __threadfence();             // agent acquire: invalidate L2
    }
    __syncthreads();
}

struct GcnSmem {
    float red[8][2][16][16];
    unsigned short wtile[16 * 40];
};

// one GCN layer: out = relu(A @ G + b) [@ Wnext]; 256 blocks x 512 thr
template <int NIN, int NOUT, bool LAST>
__device__ inline void gcn_phase(GcnSmem& sm, const unsigned short* __restrict__ A16,
                                 const unsigned short* __restrict__ Gt,
                                 const float* __restrict__ bias,
                                 const float* __restrict__ W,
                                 unsigned short* __restrict__ Gout,
                                 int mt, int tid) {
    constexpr int T = NIN / 16;
    int w = tid >> 6, lane = tid & 63, m = lane & 15, q = lane >> 4;
    int kw = w * 512;

    const unsigned short* arow = A16 + (size_t)(mt * 16 + m) * 4096 + kw + q * 8;
    f32x4 acc[T];
    #pragma unroll
    for (int t = 0; t < T; t++) acc[t] = (f32x4){0.f, 0.f, 0.f, 0.f};

    bf16x8 wfrag;
    if (!LAST && w < NOUT / 16) {
        #pragma unroll
        for (int j = 0; j < 8; j++) {
            int ci = q * 8 + j;
            wfrag[j] = (ci < NIN) ? (short)bfb(W[ci * NOUT + w * 16 + m]) : (short)0;
        }
    }

    #pragma unroll 4
    for (int s = 0; s < 16; s++) {
        bf16x8 bA = *(const bf16x8*)(arow + s * 32);
        #pragma unroll
        for (int t = 0; t < T; t++) {
            bf16x8 af = *(const bf16x8*)(Gt + (size_t)(t * 16 + m) * 4096 + kw + q * 8 + s * 32);
            acc[t] = __builtin_amdgcn_mfma_f32_16x16x32_bf16(af, bA, acc[t], 0, 0, 0);
        }
    }
    #pragma unroll
    for (int t = 0; t < T; t++)
        #pragma unroll
        for (int r = 0; r < 4; r++) sm.red[w][t][q * 4 + r][m] = acc[t][r];
    __syncthreads();

    if (tid < T * 256) {
        int dstp = tid & 15, cop = (tid >> 4) & 15, t = tid >> 8;
        float sum = 0.f;
        #pragma unroll
        for (int w8 = 0; w8 < 8; w8++) sum += sm.red[w8][t][cop][dstp];
        int co = t * 16 + cop;
        float val = fmaxf(sum + bias[co], 0.f);
        if (LAST) Gout[(size_t)(mt * 16 + dstp) * 32 + co] = bfb(val);
        else      sm.wtile[dstp * 40 + co] = bfb(val);
    }
    if (!LAST && NIN == 16 && tid >= 256 && tid < 512) {
        int idx = tid - 256;
        sm.wtile[(idx & 15) * 40 + 16 + ((idx >> 4) & 15)] = 0;
    }
    __syncthreads();

    if (!LAST && w < NOUT / 16) {
        bf16x8 af = *(const bf16x8*)&sm.wtile[m * 40 + q * 8];
        f32x4 o = (f32x4){0.f, 0.f, 0.f, 0.f};
        o = __builtin_amdgcn_mfma_f32_16x16x32_bf16(af, wfrag, o, 0, 0, 0);
        uint2 ov;
        ov.x = (unsigned int)bfb(o[0]) | ((unsigned int)bfb(o[1]) << 16);
        ov.y = (unsigned int)bfb(o[2]) | ((unsigned int)bfb(o[3]) << 16);
        *(uint2*)&Gout[(size_t)(w * 16 + m) * 4096 + mt * 16 + q * 4] = ov;
    }
    __syncthreads();
}

// mega-kernel: zero + deg + scatter + 3 GCN layers, grid-barrier separated
__global__ __launch_bounds__(512) void k_graph(
        const int* __restrict__ ei, const float* __restrict__ ew,
        const float* __restrict__ x, const float* __restrict__ W0,
        const float* __restrict__ b0, const float* __restrict__ W1,
        const float* __restrict__ b1, const float* __restrict__ W2,
        const float* __restrict__ b2, const float* __restrict__ Wp,
        unsigned int* __restrict__ w2, float* __restrict__ deg,
        unsigned short* __restrict__ A16,
        unsigned short* __restrict__ G1T, unsigned short* __restrict__ G2T,
        unsigned short* __restrict__ G3T, unsigned short* __restrict__ H3,
        unsigned int* __restrict__ bars) {
    __shared__ GcnSmem sm;
    int blk = blockIdx.x, tid = threadIdx.x;
    int gid = blk * 512 + tid;

    // ---- P0: zero A strip (+deg by block 0) ----
    {
        uint4 z4 = {0u, 0u, 0u, 0u};
        uint4* ap = (uint4*)(A16 + (size_t)blk * 16 * 4096);
        #pragma unroll
        for (int k = 0; k < 16; k++) ap[tid + k * 512] = z4;
        if (blk == 0) {
            float4 zf = {0.f, 0.f, 0.f, 0.f};
            float4* dp = (float4*)deg;
            dp[tid * 2] = zf;
            dp[tid * 2 + 1] = zf;
        }
    }
    gbar(&bars[0]);

    // ---- P1: degree atomics (grid == E exactly) ----
    atomicAdd(&deg[ei[NE + gid]], ew[gid]);
    gbar(&bars[1]);

    // ---- P2: scatter A + diag + G1T + conv-weight pack ----
    {
        int s = ei[gid], d = ei[NE + gid];
        float v = rsqrtf(deg[s] + 2.f) * ew[gid] * rsqrtf(deg[d] + 2.f);
        atomic_add_bf16(A16, (unsigned int)d * 4096u + (unsigned int)s, v);
        if (gid < NT * 16) {
            int node = gid & 4095, co = gid >> 12;
            const float4* xr = (const float4*)(x + node * 32);
            float a = 0.f;
            #pragma unroll
            for (int r = 0; r < 8; r++) {
                float4 f = xr[r];
                a += f.x * W0[(r*4+0)*16 + co] + f.y * W0[(r*4+1)*16 + co]
                   + f.z * W0[(r*4+2)*16 + co] + f.w * W0[(r*4+3)*16 + co];
            }
            G1T[co * 4096 + node] = bfb(a);
        }
        if (gid >= NT * 16 && gid < NT * 16 + 1568) {
            int k = gid - NT * 16;
            __half hh = __float2half(Wp[k]);
            __half2 h2 = __halves2half2(hh, hh);
            w2[k] = *(unsigned int*)&h2;
        }
        if (gid >= NE - NT) {
            int n = gid - (NE - NT);
            atomic_add_bf16(A16, (unsigned int)n * 4097u, 2.f / (deg[n] + 2.f));
        }
    }
    gbar(&bars[2]);

    gcn_phase<16, 32, false>(sm, A16, G1T, b0, W1, G2T, blk, tid);
    gbar(&bars[3]);
    gcn_phase<32, 32, false>(sm, A16, G2T, b1, W2, G3T, blk, tid);
    gbar(&bars[4]);
    gcn_phase<32, 32, true >(sm, A16, G3T, b2, nullptr, H3, blk, tid);
}

// ---------------- fused C1 + 7x7 conv + sigmoid (unchanged from r6) ----------------

__global__ __launch_bounds__(512) void k_cc(const unsigned short* __restrict__ h3,
                                            const float* __restrict__ Wc,
                                            const float* __restrict__ bc,
                                            const unsigned int* __restrict__ w2,
                                            const float* __restrict__ bp,
                                            float* __restrict__ out) {
    __shared__ unsigned short zs[256 * 40];
    __shared__ float wcs[32 * 36];
    __shared__ __align__(16) unsigned short ct[4 * 32 * 272];
    __shared__ __align__(16) unsigned short pt[4][4096];

    int band = blockIdx.x, bb = blockIdx.y;
    int i0 = band * 16;
    int tid = threadIdx.x;
    int lane = tid & 63, w = tid >> 6;
    int m = lane & 15, q = lane >> 4;

    {
        int row = tid >> 1, half = tid & 1;
        const uint4* src = (const uint4*)(h3 + (size_t)(bb * 256 + row) * 32) + half * 2;
        uint4 v0 = src[0], v1 = src[1];
        uint4* dst = (uint4*)&zs[row * 40 + half * 16];
        dst[0] = v0; dst[1] = v1;
    }
    #pragma unroll
    for (int k = tid; k < 1024; k += 512) wcs[(k >> 5) * 36 + (k & 31)] = Wc[k];
    for (int k = tid; k < 4 * 32 * 136; k += 512) ((unsigned int*)ct)[k] = 0;
    __syncthreads();

    bf16x8 bt[2];
    bool wok[2];
    #pragma unroll
    for (int nt = 0; nt < 2; nt++) {
        int r = i0 - 3 + nt * 16 + m;
        wok[nt] = (unsigned)r < 256u;
        r = r < 0 ? 0 : (r > 255 ? 255 : r);
        bt[nt] = *(const bf16x8*)&zs[r * 40 + q * 8];
    }
    float zaf[2][8];
    #pragma unroll
    for (int jt2 = 0; jt2 < 2; jt2++) {
        bf16x8 za = *(const bf16x8*)&zs[((w * 2 + jt2) * 16 + m) * 40 + q * 8];
        #pragma unroll
        for (int e = 0; e < 8; e++)
            zaf[jt2][e] = __uint_as_float(((unsigned int)(unsigned short)za[e]) << 16);
    }

    int gg = tid >> 7, tx = tid & 31, ty = (tid >> 5) & 3;
    __half2 acc[4][4];
    __half2 zh = __float2half2_rn(0.f);
    #pragma unroll
    for (int o = 0; o < 4; o++)
        #pragma unroll
        for (int p = 0; p < 4; p++) acc[o][p] = zh;

    for (int it = 0; it < 8; it++) {
        #pragma unroll
        for (int g = 0; g < 4; g++) {
            int h = it * 4 + g;
            float wf[8];
            *(float4*)&wf[0] = *(const float4*)&wcs[h * 36 + q * 8];
            *(float4*)&wf[4] = *(const float4*)&wcs[h * 36 + q * 8 + 4];
            float bch = bc[h];
            #pragma unroll
            for (int jt2 = 0; jt2 < 2; jt2++) {
                bf16x8 afv;
                #pragma unroll
                for (int e = 0; e < 8; e++) afv[e] = (short)bfb(zaf[jt2][e] * wf[e]);
                int pos = 4 + (w * 2 + jt2) * 16 + q * 4;
                #pragma unroll
                for (int nt = 0; nt < 2; nt++) {
                    f32x4 d = (f32x4){0.f, 0.f, 0.f, 0.f};
                    d = __builtin_amdgcn_mfma_f32_16x16x32_bf16(afv, bt[nt], d, 0, 0, 0);
                    if (wok[nt]) {
                        float v0 = fmaxf(d[0] + bch, 0.f);
                        float v1 = fmaxf(d[1] + bch, 0.f);
                        float v2 = fmaxf(d[2] + bch, 0.f);
                        float v3 = fmaxf(d[3] + bch, 0.f);
                        __half2 h0 = __floats2half2_rn(v0, v1);
                        __half2 h1 = __floats2half2_rn(v2, v3);
                        uint2 o2;
                        o2.x = *(unsigned int*)&h0;
                        o2.y = *(unsigned int*)&h1;
                        *(uint2*)&ct[g * 8704 + (nt * 16 + m) * 272 + pos] = o2;
                    }
                }
            }
        }
        __syncthreads();

        {
            const unsigned short* C = ct + gg * 8704;
            const __half2* wrow = (const __half2*)w2 + (it * 4 + gg) * 49;
            #pragma unroll
            for (int dr = 0; dr < 10; dr++) {
                const uint4* p4 = (const uint4*)&C[(ty * 4 + dr) * 272 + tx * 8];
                uint4 ua = p4[0], ub = p4[1];
                unsigned int E[8] = {ua.x, ua.y, ua.z, ua.w, ub.x, ub.y, ub.z, ub.w};
                unsigned int O[7];
                #pragma unroll
                for (int k = 0; k < 7; k++) O[k] = align16(E[k + 1], E[k]);
                #pragma unroll
                for (int o = 0; o < 4; o++) {
                    if (dr - o < 0 || dr - o > 6) continue;
                    int di = dr - o;
                    #pragma unroll
                    for (int dj = 0; dj < 7; dj++) {
                        __half2 wv = wrow[di * 7 + dj];
                        #pragma unroll
                        for (int pr = 0; pr < 4; pr++) {
                            int s = 2 * pr + dj + 1;
                            unsigned int pv = (s & 1) ? O[s >> 1] : E[s >> 1];
                            acc[o][pr] = __hfma2(wv, *(__half2*)&pv, acc[o][pr]);
                        }
                    }
                }
            }
        }
        __syncthreads();
    }

    #pragma unroll
    for (int o = 0; o < 4; o++) {
        uint4 v;
        v.x = *(unsigned int*)&acc[o][0];
        v.y = *(unsigned int*)&acc[o][1];
        v.z = *(unsigned int*)&acc[o][2];
        v.w = *(unsigned int*)&acc[o][3];
        *(uint4*)&pt[gg][(ty * 4 + o) * 256 + tx * 8] = v;
    }
    __syncthreads();

    {
        int base = tid * 8;
        float fs[8];
        #pragma unroll
        for (int e = 0; e < 8; e++) fs[e] = 0.f;
        #pragma unroll
        for (int g = 0; g < 4; g++) {
            uint4 v = *(const uint4*)&pt[g][base];
            unsigned int uu[4] = {v.x, v.y, v.z, v.w};
            #pragma unroll
            for (int d = 0; d < 4; d++) {
                float2 f = __half22float2(*(__half2*)&uu[d]);
                fs[2 * d] += f.x; fs[2 * d + 1] += f.y;
            }
        }
        float bpv = bp[0];
        float rs[8];
        #pragma unroll
        for (int e = 0; e < 8; e++) rs[e] = 1.0f / (1.0f + __expf(-(fs[e] + bpv)));
        int row = base >> 8, col = base & 255;
        float* op = &out[((size_t)(bb * 256) + i0 + row) * 256 + col];
        *(float4*)op = make_float4(rs[0], rs[1], rs[2], rs[3]);
        *(float4*)(op + 4) = make_float4(rs[4], rs[5], rs[6], rs[7]);
    }
}

// ---------------- launch ----------------

extern "C" void kernel_launch(void* const* d_in, const int* in_sizes, int n_in,
                              void* d_out, int out_size, void* d_ws, size_t ws_size,
                              hipStream_t stream) {
    const float* x  = (const float*)d_in[0];
    const int*   ei = (const int*)d_in[1];
    const float* ew = (const float*)d_in[2];
    const float* W0 = (const float*)d_in[4];
    const float* b0 = (const float*)d_in[5];
    const float* W1 = (const float*)d_in[6];
    const float* b1 = (const float*)d_in[7];
    const float* W2 = (const float*)d_in[8];
    const float* b2 = (const float*)d_in[9];
    const float* Wc = (const float*)d_in[10];
    const float* bc = (const float*)d_in[11];
    const float* Wp = (const float*)d_in[12];
    const float* bp = (const float*)d_in[13];

    char* ws = (char*)d_ws;
    float*          deg  = (float*)(ws + OFF_DEG);
    unsigned short* A16  = (unsigned short*)(ws + OFF_A);
    unsigned short* G1T  = (unsigned short*)(ws + OFF_G1T);
    unsigned short* G2T  = (unsigned short*)(ws + OFF_G2T);
    unsigned short* G3T  = (unsigned short*)(ws + OFF_G3T);
    unsigned short* H3   = (unsigned short*)(ws + OFF_H3);
    unsigned int*   w2t  = (unsigned int*)(ws + OFF_W2T);
    unsigned int*   bars = (unsigned int*)(ws + OFF_BAR);

    (void)hipMemsetAsync(bars, 0, 64, stream);   // barrier counters only

    k_graph<<<NBLK, 512, 0, stream>>>(ei, ew, x, W0, b0, W1, b1, W2, b2,
                                      Wp, w2t, deg, A16, G1T, G2T, G3T, H3, bars);
    k_cc<<<dim3(16, 16), 512, 0, stream>>>(H3, Wc, bc, w2t, bp, (float*)d_out);
}

// Round 8
// 206.556 us; speedup vs baseline: 1.3592x; 1.3592x over previous
//
#include <hip/hip_runtime.h>
#include <hip/hip_bf16.h>
#include <hip/hip_fp16.h>

#define NT 4096
#define NE 131072

// ws layout (bytes)
#define OFF_DEG  0            // float[4096]
#define OFF_A    16384        // bf16[4096*4096] = 32 MiB
#define OFF_G1T  33570816     // bf16[16][4096]
#define OFF_G2T  33701888     // bf16[32][4096]
#define OFF_G3T  33964032     // bf16[32][4096]
#define OFF_H3   34226176     // bf16[4096][32]
#define OFF_W2T  34488320     // uint[1568]
// total ~34.5 MB

typedef __attribute__((ext_vector_type(8))) short bf16x8;
typedef __attribute__((ext_vector_type(4))) float f32x4;

__device__ inline unsigned int align16(unsigned int hi, unsigned int lo) {
#if __has_builtin(__builtin_amdgcn_alignbit)
    return __builtin_amdgcn_alignbit(hi, lo, 16);
#else
    return (lo >> 16) | (hi << 16);
#endif
}

__device__ inline unsigned short bfb(float x) {
    return __hip_bfloat16_raw(__float2bfloat16(x)).x;
}

__device__ inline void atomic_add_bf16(unsigned short* base, unsigned int idx, float v) {
    unsigned long long addr = (unsigned long long)(base + (idx & ~1u));
    unsigned int bits = ((unsigned int)bfb(v)) << ((idx & 1u) * 16);
    asm volatile("global_atomic_pk_add_bf16 %0, %1, off" :: "v"(addr), "v"(bits) : "memory");
}

// ---------------- setup ----------------

// zero dense A (streaming) + degree atomics; deg pre-zeroed by tiny memset
__global__ __launch_bounds__(256) void k_zerodeg(const int* __restrict__ ei,
                                                 const float* __restrict__ ew,
                                                 float* __restrict__ deg,
                                                 unsigned short* __restrict__ A16) {
    int blk = blockIdx.x, tid = threadIdx.x;
    uint4 z4 = {0u, 0u, 0u, 0u};
    uint4* ap = (uint4*)(A16 + (size_t)blk * 16384);
    #pragma unroll
    for (int k = 0; k < 8; k++) ap[tid + k * 256] = z4;
    int gid = blk * 256 + tid;
    if (gid < NE) atomicAdd(&deg[ei[NE + gid]], ew[gid]);
}

__global__ void k_scatter(const int* __restrict__ ei, const float* __restrict__ ew,
                          const float* __restrict__ deg, unsigned short* __restrict__ A16,
                          const float* __restrict__ x, const float* __restrict__ W0,
                          unsigned short* __restrict__ G1T,
                          const float* __restrict__ Wp, unsigned int* __restrict__ w2) {
    int e = blockIdx.x * 256 + threadIdx.x;
    if (e < NE) {
        int s = ei[e], d = ei[NE + e];
        float v = rsqrtf(deg[s] + 2.f) * ew[e] * rsqrtf(deg[d] + 2.f);
        atomic_add_bf16(A16, (unsigned int)d * 4096u + (unsigned int)s, v);
    }
    if (e < NT) {
        atomic_add_bf16(A16, (unsigned int)e * 4097u, 2.f / (deg[e] + 2.f));
    }
    if (e < NT * 16) {
        int node = e & 4095, co = e >> 12;
        const float4* xr = (const float4*)(x + node * 32);
        float a = 0.f;
        #pragma unroll
        for (int r = 0; r < 8; r++) {
            float4 f = xr[r];
            a += f.x * W0[(r*4+0)*16 + co] + f.y * W0[(r*4+1)*16 + co]
               + f.z * W0[(r*4+2)*16 + co] + f.w * W0[(r*4+3)*16 + co];
        }
        G1T[co * 4096 + node] = bfb(a);
    }
    if (e >= NE - 1568) {
        int k = e - (NE - 1568);
        __half hh = __float2half(Wp[k]);
        __half2 h2 = __halves2half2(hh, hh);
        w2[k] = *(unsigned int*)&h2;
    }
}

// ---------------- GCN layer via dense-A MFMA ----------------

template <int NIN, int NOUT, bool LAST>
__global__ __launch_bounds__(512) void k_gcn(const unsigned short* __restrict__ A16,
                                             const unsigned short* __restrict__ Gt,
                                             const float* __restrict__ bias,
                                             const float* __restrict__ W,
                                             unsigned short* __restrict__ Gout) {
    constexpr int T = NIN / 16;
    __shared__ float red[8][T][16][16];
    __shared__ unsigned short wtile[16 * 40];
    int mt = blockIdx.x;
    int tid = threadIdx.x;
    int w = tid >> 6, lane = tid & 63, m = lane & 15, q = lane >> 4;
    int kw = w * 512;

    const unsigned short* arow = A16 + (size_t)(mt * 16 + m) * 4096 + kw + q * 8;
    f32x4 acc[T];
    #pragma unroll
    for (int t = 0; t < T; t++) acc[t] = (f32x4){0.f, 0.f, 0.f, 0.f};

    bf16x8 wfrag;
    if (!LAST && w < NOUT / 16) {
        #pragma unroll
        for (int j = 0; j < 8; j++) {
            int ci = q * 8 + j;
            wfrag[j] = (ci < NIN) ? (short)bfb(W[ci * NOUT + w * 16 + m]) : (short)0;
        }
    }

    #pragma unroll 4
    for (int s = 0; s < 16; s++) {
        bf16x8 bA = *(const bf16x8*)(arow + s * 32);
        #pragma unroll
        for (int t = 0; t < T; t++) {
            bf16x8 af = *(const bf16x8*)(Gt + (size_t)(t * 16 + m) * 4096 + kw + q * 8 + s * 32);
            acc[t] = __builtin_amdgcn_mfma_f32_16x16x32_bf16(af, bA, acc[t], 0, 0, 0);
        }
    }
    #pragma unroll
    for (int t = 0; t < T; t++)
        #pragma unroll
        for (int r = 0; r < 4; r++) red[w][t][q*4 + r][m] = acc[t][r];
    __syncthreads();

    if (tid < T * 256) {
        int dstp = tid & 15, cop = (tid >> 4) & 15, t = tid >> 8;
        float sum = 0.f;
        #pragma unroll
        for (int w8 = 0; w8 < 8; w8++) sum += red[w8][t][cop][dstp];
        int co = t * 16 + cop;
        float val = fmaxf(sum + bias[co], 0.f);
        if (LAST) Gout[(size_t)(mt * 16 + dstp) * 32 + co] = bfb(val);
        else      wtile[dstp * 40 + co] = bfb(val);
    }
    if (!LAST && NIN == 16 && tid >= 256 && tid < 512) {
        int idx = tid - 256;
        wtile[(idx & 15) * 40 + 16 + ((idx >> 4) & 15)] = 0;
    }
    __syncthreads();

    if (!LAST && w < NOUT / 16) {
        bf16x8 af = *(const bf16x8*)&wtile[m * 40 + q * 8];
        f32x4 o = (f32x4){0.f, 0.f, 0.f, 0.f};
        o = __builtin_amdgcn_mfma_f32_16x16x32_bf16(af, wfrag, o, 0, 0, 0);
        uint2 ov;
        ov.x = (unsigned int)bfb(o[0]) | ((unsigned int)bfb(o[1]) << 16);
        ov.y = (unsigned int)bfb(o[2]) | ((unsigned int)bfb(o[3]) << 16);
        *(uint2*)&Gout[(size_t)(w * 16 + m) * 4096 + mt * 16 + q * 4] = ov;
    }
}

// ---------------- fused C1 + 7x7 conv + sigmoid ----------------
// grid (band 32, b 16) = 512 blocks (2/CU); 512 thr. Band = 8 out rows.
// Per iter (16): MFMA 2 channels of c[h]=relu(Zw_h Z^T+bc) into 2 LDS planes
// (16 rows i0-3..i0+12, f16, stride 272, col j+4, halos zero); then 2x256-thr
// conv groups, 1 out-row x 8 px per thread. End: 2-way reduce+sigmoid+store.

__global__ __launch_bounds__(512, 4) void k_cc(const unsigned short* __restrict__ h3,
                                               const float* __restrict__ Wc,
                                               const float* __restrict__ bc,
                                               const unsigned int* __restrict__ w2,
                                               const float* __restrict__ bp,
                                               float* __restrict__ out) {
    __shared__ unsigned short zs[256 * 40];                    // 20480 B
    __shared__ float wcs[32 * 36];                             // 4608 B
    __shared__ __align__(16) unsigned short ct[2 * 16 * 272];  // 17408 B
    __shared__ __align__(16) unsigned short pt[2][2048];       // 8192 B

    int band = blockIdx.x, bb = blockIdx.y;
    int i0 = band * 8;
    int tid = threadIdx.x;
    int lane = tid & 63, w = tid >> 6;
    int m = lane & 15, q = lane >> 4;

    // ---- stage Z_b ----
    {
        int row = tid >> 1, half = tid & 1;
        const uint4* src = (const uint4*)(h3 + (size_t)(bb * 256 + row) * 32) + half * 2;
        uint4 v0 = src[0], v1 = src[1];
        uint4* dst = (uint4*)&zs[row * 40 + half * 16];
        dst[0] = v0; dst[1] = v1;
    }
    #pragma unroll
    for (int k = tid; k < 1024; k += 512) wcs[(k >> 5) * 36 + (k & 31)] = Wc[k];
    for (int k = tid; k < 2 * 16 * 136; k += 512) ((unsigned int*)ct)[k] = 0;
    __syncthreads();

    // ---- frags ----
    bf16x8 bt;          // B operand: i-rows (one 16-row tile)
    bool wok;
    {
        int r = i0 - 3 + m;
        wok = (unsigned)r < 256u;
        r = r < 0 ? 0 : (r > 255 ? 255 : r);
        bt = *(const bf16x8*)&zs[r * 40 + q * 8];
    }
    float zaf[2][8];    // A base: j-rows
    #pragma unroll
    for (int jt2 = 0; jt2 < 2; jt2++) {
        bf16x8 za = *(const bf16x8*)&zs[((w * 2 + jt2) * 16 + m) * 40 + q * 8];
        #pragma unroll
        for (int e = 0; e < 8; e++)
            zaf[jt2][e] = __uint_as_float(((unsigned int)(unsigned short)za[e]) << 16);
    }

    int gg = tid >> 8, idx = tid & 255;
    int tx = idx & 31, ty = idx >> 5;          // 8 px, 1 out row
    __half2 acc[4];
    __half2 zh = __float2half2_rn(0.f);
    #pragma unroll
    for (int p = 0; p < 4; p++) acc[p] = zh;

    for (int it = 0; it < 16; it++) {
        // ---- MFMA phase: channels it*2, it*2+1 ----
        #pragma unroll
        for (int g = 0; g < 2; g++) {
            int h = it * 2 + g;
            float wf[8];
            *(float4*)&wf[0] = *(const float4*)&wcs[h * 36 + q * 8];
            *(float4*)&wf[4] = *(const float4*)&wcs[h * 36 + q * 8 + 4];
            float bch = bc[h];
            #pragma unroll
            for (int jt2 = 0; jt2 < 2; jt2++) {
                bf16x8 afv;
                #pragma unroll
                for (int e = 0; e < 8; e++) afv[e] = (short)bfb(zaf[jt2][e] * wf[e]);
                int pos = 4 + (w * 2 + jt2) * 16 + q * 4;
                f32x4 d = (f32x4){0.f, 0.f, 0.f, 0.f};
                d = __builtin_amdgcn_mfma_f32_16x16x32_bf16(afv, bt, d, 0, 0, 0);
                if (wok) {
                    float v0 = fmaxf(d[0] + bch, 0.f);
                    float v1 = fmaxf(d[1] + bch, 0.f);
                    float v2 = fmaxf(d[2] + bch, 0.f);
                    float v3 = fmaxf(d[3] + bch, 0.f);
                    __half2 h0 = __floats2half2_rn(v0, v1);
                    __half2 h1 = __floats2half2_rn(v2, v3);
                    uint2 o2;
                    o2.x = *(unsigned int*)&h0;
                    o2.y = *(unsigned int*)&h1;
                    *(uint2*)&ct[g * 4352 + m * 272 + pos] = o2;
                }
            }
        }
        __syncthreads();

        // ---- conv phase: group gg convs channel it*2+gg ----
        {
            const unsigned short* C = ct + gg * 4352;
            const __half2* wrow = (const __half2*)w2 + (it * 2 + gg) * 49;
            #pragma unroll
            for (int dr = 0; dr < 7; dr++) {
                const uint4* p4 = (const uint4*)&C[(ty + dr) * 272 + tx * 8];
                uint4 ua = p4[0], ub = p4[1];
                unsigned int E[8] = {ua.x, ua.y, ua.z, ua.w, ub.x, ub.y, ub.z, ub.w};
                unsigned int O[7];
                #pragma unroll
                for (int k = 0; k < 7; k++) O[k] = align16(E[k + 1], E[k]);
                #pragma unroll
                for (int dj = 0; dj < 7; dj++) {
                    __half2 wv = wrow[dr * 7 + dj];
                    #pragma unroll
                    for (int pr = 0; pr < 4; pr++) {
                        int s = 2 * pr + dj + 1;
                        unsigned int pv = (s & 1) ? O[s >> 1] : E[s >> 1];
                        acc[pr] = __hfma2(wv, *(__half2*)&pv, acc[pr]);
                    }
                }
            }
        }
        __syncthreads();
    }

    // ---- write partials, reduce, sigmoid, store ----
    {
        uint4 v;
        v.x = *(unsigned int*)&acc[0];
        v.y = *(unsigned int*)&acc[1];
        v.z = *(unsigned int*)&acc[2];
        v.w = *(unsigned int*)&acc[3];
        *(uint4*)&pt[gg][ty * 256 + tx * 8] = v;
    }
    __syncthreads();

    {
        int base = tid * 4;
        float fs[4];
        #pragma unroll
        for (int e = 0; e < 4; e++) fs[e] = 0.f;
        #pragma unroll
        for (int g = 0; g < 2; g++) {
            uint2 v = *(const uint2*)&pt[g][base];
            unsigned int uu[2] = {v.x, v.y};
            #pragma unroll
            for (int d = 0; d < 2; d++) {
                float2 f = __half22float2(*(__half2*)&uu[d]);
                fs[2 * d] += f.x; fs[2 * d + 1] += f.y;
            }
        }
        float bpv = bp[0];
        float4 r;
        r.x = 1.0f / (1.0f + __expf(-(fs[0] + bpv)));
        r.y = 1.0f / (1.0f + __expf(-(fs[1] + bpv)));
        r.z = 1.0f / (1.0f + __expf(-(fs[2] + bpv)));
        r.w = 1.0f / (1.0f + __expf(-(fs[3] + bpv)));
        int row = base >> 8, col = base & 255;
        *(float4*)&out[((size_t)(bb * 256) + i0 + row) * 256 + col] = r;
    }
}

// ---------------- launch ----------------

extern "C" void kernel_launch(void* const* d_in, const int* in_sizes, int n_in,
                              void* d_out, int out_size, void* d_ws, size_t ws_size,
                              hipStream_t stream) {
    const float* x  = (const float*)d_in[0];
    const int*   ei = (const int*)d_in[1];
    const float* ew = (const float*)d_in[2];
    const float* W0 = (const float*)d_in[4];
    const float* b0 = (const float*)d_in[5];
    const float* W1 = (const float*)d_in[6];
    const float* b1 = (const float*)d_in[7];
    const float* W2 = (const float*)d_in[8];
    const float* b2 = (const float*)d_in[9];
    const float* Wc = (const float*)d_in[10];
    const float* bc = (const float*)d_in[11];
    const float* Wp = (const float*)d_in[12];
    const float* bp = (const float*)d_in[13];

    char* ws = (char*)d_ws;
    float*          deg  = (float*)(ws + OFF_DEG);
    unsigned short* A16  = (unsigned short*)(ws + OFF_A);
    unsigned short* G1T  = (unsigned short*)(ws + OFF_G1T);
    unsigned short* G2T  = (unsigned short*)(ws + OFF_G2T);
    unsigned short* G3T  = (unsigned short*)(ws + OFF_G3T);
    unsigned short* H3   = (unsigned short*)(ws + OFF_H3);
    unsigned int*   w2t  = (unsigned int*)(ws + OFF_W2T);

    (void)hipMemsetAsync(deg, 0, 16384, stream);   // deg only (A zeroed in-kernel)

    k_zerodeg<<<1024, 256, 0, stream>>>(ei, ew, deg, A16);
    k_scatter<<<NE/256, 256, 0, stream>>>(ei, ew, deg, A16, x, W0, G1T, Wp, w2t);

    k_gcn<16, 32, false><<<256, 512, 0, stream>>>(A16, G1T, b0, W1, G2T);
    k_gcn<32, 32, false><<<256, 512, 0, stream>>>(A16, G2T, b1, W2, G3T);
    k_gcn<32, 32, true> <<<256, 512, 0, stream>>>(A16, G3T, b2, nullptr, H3);

    k_cc<<<dim3(32, 16), 512, 0, stream>>>(H3, Wc, bc, w2t, bp, (float*)d_out);
}